// Round 16
// baseline (203.243 us; speedup 1.0000x reference)
//
#include <hip/hip_runtime.h>

// SparseResidualBlock: bn1->silu->sparseconv1(+t_emb)->bn2->silu->sparseconv2 + (x@res_W+res_b)
// N=50000, FIN=64, FOUT=128, K=27, B=4, TEMB=256. Output f32 [N,128].
//
// R16: time model = periods x ~1300cyc / co-resident-blocks-per-CU (R8/R13/
// R15 invariance). Lever: fout-split x2 across BLOCKS (no atomics, no extra
// regs): block (vb,h) does 64 voxels x 64 fout. Grid 1564, waves 3126
// (12/CU, 2x R15). acc halves to f32x16[2]; stage halves (16KB/tap conv2).
// Pipeline = R15's (B-prefetch depth 1, one __syncthreads/period, 27 periods).
// 32x32x16 MFMA kept (A-traffic win). No VGPR cap / no NT / no 3rd buffer.

#define EPS 1e-5f

typedef __attribute__((ext_vector_type(8))) short s16x8;
typedef __attribute__((ext_vector_type(4))) float f32x4;
typedef __attribute__((ext_vector_type(16))) float f32x16;
typedef __attribute__((ext_vector_type(4))) unsigned short u16x4;

static __device__ __forceinline__ unsigned short f2bf(float f) {
    union { float f; unsigned u; } v; v.f = f;
    unsigned r = v.u + 0x7fffu + ((v.u >> 16) & 1u);   // RTNE
    return (unsigned short)(r >> 16);
}
static __device__ __forceinline__ float silu_d(float x) {
    return x / (1.f + __expf(-x));
}
static __device__ __forceinline__ void gload_lds16(const void* gsrc, void* ldst) {
    __builtin_amdgcn_global_load_lds(
        (const __attribute__((address_space(1))) unsigned int*)gsrc,
        (__attribute__((address_space(3))) unsigned int*)ldst, 16, 0, 0);
}
// mask stored as 1-byte bool (shift 0) or int32 (shift 2)? Probe a byte at a
// non-multiple-of-4 index inside the all-true center row (k=13).
static __device__ __forceinline__ int mask_shift(const unsigned char* mask, int NV) {
    size_t base = (size_t)13 * (size_t)NV;
    int v = ((base & 3) == 3) ? 2 : 1;
    return (mask[base + v] == 1) ? 0 : 2;
}

// ---------------- prep: t_emb + bn2 scale/shift ----------------
__global__ void k_prep_small(const float* __restrict__ t, const float* __restrict__ tW,
                             const float* __restrict__ tb,
                             const float* __restrict__ g2, const float* __restrict__ b2,
                             const float* __restrict__ m2, const float* __restrict__ v2,
                             float* __restrict__ temb, float* __restrict__ sc,
                             float* __restrict__ sh, int B) {
    int tid = threadIdx.x;
    if (tid < B * 128) {
        int b = tid >> 7, o = tid & 127;
        float s = 0.f;
        for (int e = 0; e < 256; ++e) {
            float tv = t[b * 256 + e];
            s += silu_d(tv) * tW[e * 128 + o];
        }
        temb[tid] = s + tb[o];
    }
    if (tid < 128) {
        float rstd = rsqrtf(v2[tid] + EPS);
        float s1 = g2[tid] * rstd;
        sc[tid] = s1;
        sh[tid] = b2[tid] - m2[tid] * s1;
    }
}

// ---------------- prep: shuffle weights, fout-half-grouped 32x32x16 frags ----------------
// A-frag elem[lane*8+j] = W[ko][fin = ks*16 + (lane>>5)*8 + j][fout]
// W1s: frag f: mt2=f&1, ks=(f>>1)&3, h=(f>>3)&1, ko=f>>4.  (ko,h) chunk = 8KB.
// W2s: frag f: mt2=f&1, ks=(f>>1)&7, h=(f>>4)&1, ko=f>>5.  (ko,h) chunk = 16KB.
// rWs: frag f: mt=f&3, ks=f>>2 (R15 layout; conv2 indexes its half).
__global__ __launch_bounds__(256) void k_shuffle(
        const float* __restrict__ W1, const float* __restrict__ W2,
        const float* __restrict__ rW,
        unsigned short* __restrict__ W1s, unsigned short* __restrict__ W2s,
        unsigned short* __restrict__ rWs) {
    int tid = blockIdx.x * 256 + threadIdx.x;
    const int n1 = 432 * 512, n2 = 864 * 512, n3 = 16 * 512;
    if (tid < n1) {
        int f = tid >> 9, r = tid & 511, lane = r >> 3, j = r & 7;
        int mt2 = f & 1, ks = (f >> 1) & 3, h = (f >> 3) & 1, ko = f >> 4;
        int fin = ks * 16 + (lane >> 5) * 8 + j;
        int fout = (h * 2 + mt2) * 32 + (lane & 31);
        W1s[tid] = f2bf(W1[(ko * 64 + fin) * 128 + fout]);
    } else if (tid < n1 + n2) {
        int e = tid - n1;
        int f = e >> 9, r = e & 511, lane = r >> 3, j = r & 7;
        int mt2 = f & 1, ks = (f >> 1) & 7, h = (f >> 4) & 1, ko = f >> 5;
        int fin = ks * 16 + (lane >> 5) * 8 + j;
        int fout = (h * 2 + mt2) * 32 + (lane & 31);
        W2s[e] = f2bf(W2[(ko * 128 + fin) * 128 + fout]);
    } else if (tid < n1 + n2 + n3) {
        int e = tid - n1 - n2;
        int f = e >> 9, r = e & 511, lane = r >> 3, j = r & 7;
        int mt = f & 3, ks = f >> 2;
        int fin = ks * 16 + (lane >> 5) * 8 + j;
        int fout = mt * 32 + (lane & 31);
        rWs[e] = f2bf(rW[fin * 128 + fout]);
    }
}

// ---------------- elementwise: h1 = bf16(silu(bn1(x))) ----------------
__global__ __launch_bounds__(256) void k_elem(
        const float* __restrict__ x,
        const float* __restrict__ g1, const float* __restrict__ b1,
        const float* __restrict__ m1, const float* __restrict__ v1,
        unsigned short* __restrict__ h1, int NV) {
    int tid = blockIdx.x * 256 + threadIdx.x;
    if (tid >= NV * 16) return;
    int n = tid >> 4, c = (tid & 15) << 2;
    f32x4 xv = *(const f32x4*)(x + n * 64 + c);
    f32x4 gv = *(const f32x4*)(g1 + c);
    f32x4 bv = *(const f32x4*)(b1 + c);
    f32x4 mv = *(const f32x4*)(m1 + c);
    f32x4 vv = *(const f32x4*)(v1 + c);
    u16x4 ho;
#pragma unroll
    for (int j = 0; j < 4; ++j) {
        float xn = (xv[j] - mv[j]) * rsqrtf(vv[j] + EPS) * gv[j] + bv[j];
        ho[j] = f2bf(silu_d(xn));
    }
    *(u16x4*)(h1 + n * 64 + c) = ho;
}

// ================= conv1: fout-split, 32x32x16, 27-period dbuf =================
// block (vb,h): voxels [64vb,64vb+64) x fout [64h,64h+64)
__global__ __launch_bounds__(128) void k_conv1(
        const unsigned short* __restrict__ h1, const int* __restrict__ nbr,
        const unsigned char* __restrict__ mask, const unsigned short* __restrict__ W1s,
        const float* __restrict__ temb, const int* __restrict__ bidx,
        const float* __restrict__ bn2sc, const float* __restrict__ bn2sh,
        unsigned short* __restrict__ h2in, int NV) {
    __shared__ unsigned short ldsW[2][4096];   // 2 x 8KB (one (tap,half) each)
    const int vb = blockIdx.x >> 1, h = blockIdx.x & 1;
    const int lane = threadIdx.x & 63;
    const int wave = threadIdx.x >> 6;         // 0..1
    const int hi = lane >> 5, col = lane & 31;
    const int v = vb * 64 + wave * 32 + col;
    const bool vok = v < NV;
    const int msh = mask_shift(mask, NV);

    int r[27];
#pragma unroll
    for (int s = 0; s < 27; ++s) {
        r[s] = -1;
        if (vok) {
            int off = s * NV + v;
            int nv = nbr[off];
            bool mm = mask[(size_t)off << msh] != 0;
            r[s] = mm ? nv : -1;
        }
    }

    f32x16 acc[2];
#pragma unroll
    for (int m = 0; m < 2; ++m)
#pragma unroll
        for (int j = 0; j < 16; ++j) acc[m][j] = 0.f;
    const s16x8 zz = {0, 0, 0, 0, 0, 0, 0, 0};

    // prologue: stage (tap0, half h) = 8KB -> 4 x 16B per thread
    {
        const char* src = (const char*)W1s + (size_t)h * 8192 + (size_t)threadIdx.x * 16;
        char* dst = (char*)&ldsW[0][0] + (size_t)threadIdx.x * 16;
#pragma unroll
        for (int i = 0; i < 4; ++i)
            gload_lds16(src + i * 2048, dst + i * 2048);
    }
    s16x8 c[4], n[4];
    {
        int row0 = (r[0] >= 0) ? r[0] : 0;
#pragma unroll
        for (int ks = 0; ks < 4; ++ks)
            c[ks] = *(const s16x8*)(h1 + row0 * 64 + ks * 16 + hi * 8);
    }
    __syncthreads();

#pragma unroll
    for (int p = 0; p < 27; ++p) {
        if (p < 26) {
            const char* src = (const char*)W1s + ((size_t)(p + 1) * 2 + h) * 8192 + (size_t)threadIdx.x * 16;
            char* dst = (char*)&ldsW[(p + 1) & 1][0] + (size_t)threadIdx.x * 16;
#pragma unroll
            for (int i = 0; i < 4; ++i)
                gload_lds16(src + i * 2048, dst + i * 2048);
            int rn = (r[p + 1] >= 0) ? r[p + 1] : 0;
#pragma unroll
            for (int ks = 0; ks < 4; ++ks)
                n[ks] = *(const s16x8*)(h1 + rn * 64 + ks * 16 + hi * 8);
        }
        const bool m = r[p] >= 0;
        const unsigned short* wp = &ldsW[p & 1][0] + lane * 8;
#pragma unroll
        for (int ks = 0; ks < 4; ++ks) {
            s16x8 b = m ? c[ks] : zz;
#pragma unroll
            for (int mt2 = 0; mt2 < 2; ++mt2) {
                s16x8 a = *(const s16x8*)(wp + (ks * 2 + mt2) * 512);
                acc[mt2] = __builtin_amdgcn_mfma_f32_32x32x16_bf16(a, b, acc[mt2], 0, 0, 0);
            }
        }
        if (p < 26) {
            __syncthreads();
#pragma unroll
            for (int ks = 0; ks < 4; ++ks) c[ks] = n[ks];
        }
    }

    if (vok) {
        int b = bidx[v];
        const float* te = temb + b * 128;
#pragma unroll
        for (int mt2 = 0; mt2 < 2; ++mt2) {
#pragma unroll
            for (int q = 0; q < 4; ++q) {
                int cch = h * 64 + mt2 * 32 + q * 8 + hi * 4;
                f32x4 val = {acc[mt2][q * 4 + 0], acc[mt2][q * 4 + 1],
                             acc[mt2][q * 4 + 2], acc[mt2][q * 4 + 3]};
                f32x4 tv = *(const f32x4*)(te + cch);
                f32x4 sc = *(const f32x4*)(bn2sc + cch);
                f32x4 sh = *(const f32x4*)(bn2sh + cch);
                u16x4 o;
#pragma unroll
                for (int j = 0; j < 4; ++j) {
                    float zv = (val[j] + tv[j]) * sc[j] + sh[j];
                    o[j] = f2bf(silu_d(zv));
                }
                *(u16x4*)(h2in + v * 128 + cch) = o;
            }
        }
    }
}

// ================= conv2: fout-split, 32x32x16, 27-period dbuf + residual =================
__global__ __launch_bounds__(128) void k_conv2(
        const unsigned short* __restrict__ h2in, const int* __restrict__ nbr,
        const unsigned char* __restrict__ mask, const unsigned short* __restrict__ W2s,
        const float* __restrict__ x, const unsigned short* __restrict__ rWs,
        const float* __restrict__ resb, float* __restrict__ out, int NV) {
    __shared__ unsigned short ldsW[2][8192];   // 2 x 16KB (one (tap,half) each)
    const int vb = blockIdx.x >> 1, h = blockIdx.x & 1;
    const int lane = threadIdx.x & 63;
    const int wave = threadIdx.x >> 6;         // 0..1
    const int hi = lane >> 5, col = lane & 31;
    const int v = vb * 64 + wave * 32 + col;
    const bool vok = v < NV;
    const int msh = mask_shift(mask, NV);

    int r[27];
#pragma unroll
    for (int s = 0; s < 27; ++s) {
        r[s] = -1;
        if (vok) {
            int off = s * NV + v;
            int nv = nbr[off];
            bool mm = mask[(size_t)off << msh] != 0;
            r[s] = mm ? nv : -1;
        }
    }

    f32x16 acc[2];
#pragma unroll
    for (int m = 0; m < 2; ++m)
#pragma unroll
        for (int j = 0; j < 16; ++j) acc[m][j] = 0.f;
    const s16x8 zz = {0, 0, 0, 0, 0, 0, 0, 0};

    // prologue: stage (tap0, half h) = 16KB -> 8 x 16B per thread
    {
        const char* src = (const char*)W2s + (size_t)h * 16384 + (size_t)threadIdx.x * 16;
        char* dst = (char*)&ldsW[0][0] + (size_t)threadIdx.x * 16;
#pragma unroll
        for (int i = 0; i < 8; ++i)
            gload_lds16(src + i * 2048, dst + i * 2048);
    }
    s16x8 c[8], n[8];
    {
        int row0 = (r[0] >= 0) ? r[0] : 0;
#pragma unroll
        for (int ks = 0; ks < 8; ++ks)
            c[ks] = *(const s16x8*)(h2in + row0 * 128 + ks * 16 + hi * 8);
    }

    // residual GEMM for this fout half (rWs: 4ks x 4mt; our mt = h*2+mt2)
    {
        int rv = vok ? v : 0;
#pragma unroll
        for (int ks = 0; ks < 4; ++ks) {
            f32x4 xa = *(const f32x4*)(x + rv * 64 + ks * 16 + hi * 8);
            f32x4 xb = *(const f32x4*)(x + rv * 64 + ks * 16 + hi * 8 + 4);
            s16x8 b;
#pragma unroll
            for (int j = 0; j < 4; ++j) {
                b[j]     = (short)f2bf(xa[j]);
                b[j + 4] = (short)f2bf(xb[j]);
            }
#pragma unroll
            for (int mt2 = 0; mt2 < 2; ++mt2) {
                s16x8 a = *(const s16x8*)(rWs + (ks * 4 + h * 2 + mt2) * 512 + lane * 8);
                acc[mt2] = __builtin_amdgcn_mfma_f32_32x32x16_bf16(a, b, acc[mt2], 0, 0, 0);
            }
        }
    }
    __syncthreads();

#pragma unroll
    for (int p = 0; p < 27; ++p) {
        if (p < 26) {
            const char* src = (const char*)W2s + ((size_t)(p + 1) * 2 + h) * 16384 + (size_t)threadIdx.x * 16;
            char* dst = (char*)&ldsW[(p + 1) & 1][0] + (size_t)threadIdx.x * 16;
#pragma unroll
            for (int i = 0; i < 8; ++i)
                gload_lds16(src + i * 2048, dst + i * 2048);
            int rn = (r[p + 1] >= 0) ? r[p + 1] : 0;
#pragma unroll
            for (int ks = 0; ks < 8; ++ks)
                n[ks] = *(const s16x8*)(h2in + rn * 128 + ks * 16 + hi * 8);
        }
        const bool m = r[p] >= 0;
        const unsigned short* wp = &ldsW[p & 1][0] + lane * 8;
#pragma unroll
        for (int ks = 0; ks < 8; ++ks) {
            s16x8 b = m ? c[ks] : zz;
#pragma unroll
            for (int mt2 = 0; mt2 < 2; ++mt2) {
                s16x8 a = *(const s16x8*)(wp + (ks * 2 + mt2) * 512);
                acc[mt2] = __builtin_amdgcn_mfma_f32_32x32x16_bf16(a, b, acc[mt2], 0, 0, 0);
            }
        }
        if (p < 26) {
            __syncthreads();
#pragma unroll
            for (int ks = 0; ks < 8; ++ks) c[ks] = n[ks];
        }
    }

    if (vok) {
#pragma unroll
        for (int mt2 = 0; mt2 < 2; ++mt2) {
#pragma unroll
            for (int q = 0; q < 4; ++q) {
                int cch = h * 64 + mt2 * 32 + q * 8 + hi * 4;
                f32x4 val = {acc[mt2][q * 4 + 0], acc[mt2][q * 4 + 1],
                             acc[mt2][q * 4 + 2], acc[mt2][q * 4 + 3]};
                f32x4 rr = val + *(const f32x4*)(resb + cch);
                *(f32x4*)(out + v * 128 + cch) = rr;
            }
        }
    }
}

extern "C" void kernel_launch(void* const* d_in, const int* in_sizes, int n_in,
                              void* d_out, int out_size, void* d_ws, size_t ws_size,
                              hipStream_t stream) {
    const float* x          = (const float*)d_in[0];
    const int* bidx         = (const int*)d_in[1];
    const float* t          = (const float*)d_in[2];
    const int* nbr1         = (const int*)d_in[3];
    const unsigned char* mask1 = (const unsigned char*)d_in[4];
    const int* nbr2         = (const int*)d_in[5];
    const unsigned char* mask2 = (const unsigned char*)d_in[6];
    const float* bn1g       = (const float*)d_in[7];
    const float* bn1b       = (const float*)d_in[8];
    const float* bn1m       = (const float*)d_in[9];
    const float* bn1v       = (const float*)d_in[10];
    const float* W1         = (const float*)d_in[11];
    const float* tW         = (const float*)d_in[12];
    const float* tb         = (const float*)d_in[13];
    const float* bn2g       = (const float*)d_in[14];
    const float* bn2b       = (const float*)d_in[15];
    const float* bn2m       = (const float*)d_in[16];
    const float* bn2v       = (const float*)d_in[17];
    const float* W2         = (const float*)d_in[18];
    const float* rW         = (const float*)d_in[19];
    const float* resb       = (const float*)d_in[20];

    const int NV = in_sizes[0] / 64;
    const int B  = in_sizes[2] / 256;
    float* out = (float*)d_out;

    // workspace layout: small buffers first, total ~20.5 MB
    char* ws = (char*)d_ws;
    size_t o_W1s = 0;
    size_t o_W2s = o_W1s + (size_t)432 * 1024;
    size_t o_rWs = o_W2s + (size_t)864 * 1024;
    size_t o_te  = o_rWs + (size_t)16 * 1024;
    size_t o_sc  = o_te  + (size_t)B * 128 * 4;
    size_t o_sh  = o_sc  + 512;
    size_t o_h1  = o_sh  + 512;
    size_t o_h2  = o_h1  + (size_t)NV * 64 * 2;

    unsigned short* W1s  = (unsigned short*)(ws + o_W1s);
    unsigned short* W2s  = (unsigned short*)(ws + o_W2s);
    unsigned short* rWs  = (unsigned short*)(ws + o_rWs);
    float* temb  = (float*)(ws + o_te);
    float* bn2sc = (float*)(ws + o_sc);
    float* bn2sh = (float*)(ws + o_sh);
    unsigned short* h1   = (unsigned short*)(ws + o_h1);
    unsigned short* h2in = (unsigned short*)(ws + o_h2);

    k_prep_small<<<1, 512, 0, stream>>>(t, tW, tb, bn2g, bn2b, bn2m, bn2v,
                                        temb, bn2sc, bn2sh, B);
    {
        int total = (432 + 864 + 16) * 512;
        int grid = (total + 255) / 256;
        k_shuffle<<<grid, 256, 0, stream>>>(W1, W2, rW, W1s, W2s, rWs);
    }
    {
        int total = NV * 16;
        int grid = (total + 255) / 256;
        k_elem<<<grid, 256, 0, stream>>>(x, bn1g, bn1b, bn1m, bn1v, h1, NV);
    }
    {
        int NB = (NV + 63) / 64;
        k_conv1<<<NB * 2, 128, 0, stream>>>(h1, nbr1, mask1, W1s, temb, bidx,
                                            bn2sc, bn2sh, h2in, NV);
        k_conv2<<<NB * 2, 128, 0, stream>>>(h2in, nbr2, mask2, W2s, x, rWs,
                                            resb, out, NV);
    }
}

// Round 18
// 165.289 us; speedup vs baseline: 1.2296x; 1.2296x over previous
//
#include <hip/hip_runtime.h>

// SparseResidualBlock: bn1->silu->sparseconv1(+t_emb)->bn2->silu->sparseconv2 + (x@res_W+res_b)
// N=50000, FIN=64, FOUT=128, K=27, B=4, TEMB=256. Output f32 [N,128].
//
// R17 = R13 structure (16x16x32, 4 waves x 16 vox, grid 782, 2x16KB dbuf,
// one __syncthreads/period) with TWO changes:
//  1) ROLLED loops (~1KB body vs ~30KB unrolled) - I-cache hypothesis.
//  2) depth-2 B-prefetch: tap t's B gathered during tap t-1 (2-period cover),
//     nbr/mask kept in a 2-register chain (no r[27] array).
// Layouts/epilogues identical to R13. No VGPR cap / no NT loads.

#define EPS 1e-5f

typedef __attribute__((ext_vector_type(8))) short s16x8;
typedef __attribute__((ext_vector_type(4))) float f32x4;
typedef __attribute__((ext_vector_type(4))) unsigned short u16x4;

static __device__ __forceinline__ unsigned short f2bf(float f) {
    union { float f; unsigned u; } v; v.f = f;
    unsigned r = v.u + 0x7fffu + ((v.u >> 16) & 1u);   // RTNE
    return (unsigned short)(r >> 16);
}
static __device__ __forceinline__ float silu_d(float x) {
    return x / (1.f + __expf(-x));
}
static __device__ __forceinline__ void gload_lds16(const void* gsrc, void* ldst) {
    __builtin_amdgcn_global_load_lds(
        (const __attribute__((address_space(1))) unsigned int*)gsrc,
        (__attribute__((address_space(3))) unsigned int*)ldst, 16, 0, 0);
}
// mask stored as 1-byte bool (shift 0) or int32 (shift 2)? Probe a byte at a
// non-multiple-of-4 index inside the all-true center row (k=13).
static __device__ __forceinline__ int mask_shift(const unsigned char* mask, int NV) {
    size_t base = (size_t)13 * (size_t)NV;
    int v = ((base & 3) == 3) ? 2 : 1;
    return (mask[base + v] == 1) ? 0 : 2;
}

// ---------------- prep: t_emb + bn2 scale/shift ----------------
__global__ void k_prep_small(const float* __restrict__ t, const float* __restrict__ tW,
                             const float* __restrict__ tb,
                             const float* __restrict__ g2, const float* __restrict__ b2,
                             const float* __restrict__ m2, const float* __restrict__ v2,
                             float* __restrict__ temb, float* __restrict__ sc,
                             float* __restrict__ sh, int B) {
    int tid = threadIdx.x;
    if (tid < B * 128) {
        int b = tid >> 7, o = tid & 127;
        float s = 0.f;
        for (int e = 0; e < 256; ++e) {
            float tv = t[b * 256 + e];
            s += silu_d(tv) * tW[e * 128 + o];
        }
        temb[tid] = s + tb[o];
    }
    if (tid < 128) {
        float rstd = rsqrtf(v2[tid] + EPS);
        float s1 = g2[tid] * rstd;
        sc[tid] = s1;
        sh[tid] = b2[tid] - m2[tid] * s1;
    }
}

// ---------------- prep: shuffle weights to fragment-linear bf16 (16x16x32) ----------------
// frag elem[lane*8+j] = W[ko][fin=ks*32+(lane>>4)*8+j][fout=mt*16+(lane&15)]
__global__ __launch_bounds__(256) void k_shuffle(
        const float* __restrict__ W1, const float* __restrict__ W2,
        const float* __restrict__ rW,
        unsigned short* __restrict__ W1s, unsigned short* __restrict__ W2s,
        unsigned short* __restrict__ rWs) {
    int tid = blockIdx.x * 256 + threadIdx.x;
    const int n1 = 432 * 512, n2 = 864 * 512, n3 = 16 * 512;
    if (tid < n1) {
        int f = tid >> 9, r = tid & 511, lane = r >> 3, j = r & 7;
        int mt = f & 7, fk = f >> 3, ks = fk & 1, ko = fk >> 1;
        int fin = ks * 32 + (lane >> 4) * 8 + j;
        int fout = mt * 16 + (lane & 15);
        W1s[tid] = f2bf(W1[(ko * 64 + fin) * 128 + fout]);
    } else if (tid < n1 + n2) {
        int e = tid - n1;
        int f = e >> 9, r = e & 511, lane = r >> 3, j = r & 7;
        int mt = f & 7, fk = f >> 3, ks = fk & 3, ko = fk >> 2;
        int fin = ks * 32 + (lane >> 4) * 8 + j;
        int fout = mt * 16 + (lane & 15);
        W2s[e] = f2bf(W2[(ko * 128 + fin) * 128 + fout]);
    } else if (tid < n1 + n2 + n3) {
        int e = tid - n1 - n2;
        int f = e >> 9, r = e & 511, lane = r >> 3, j = r & 7;
        int mt = f & 7, ks = f >> 3;
        int fin = ks * 32 + (lane >> 4) * 8 + j;
        int fout = mt * 16 + (lane & 15);
        rWs[e] = f2bf(rW[fin * 128 + fout]);
    }
}

// ---------------- elementwise: h1 = bf16(silu(bn1(x))) ----------------
__global__ __launch_bounds__(256) void k_elem(
        const float* __restrict__ x,
        const float* __restrict__ g1, const float* __restrict__ b1,
        const float* __restrict__ m1, const float* __restrict__ v1,
        unsigned short* __restrict__ h1, int NV) {
    int tid = blockIdx.x * 256 + threadIdx.x;
    if (tid >= NV * 16) return;
    int n = tid >> 4, c = (tid & 15) << 2;
    f32x4 xv = *(const f32x4*)(x + n * 64 + c);
    f32x4 gv = *(const f32x4*)(g1 + c);
    f32x4 bv = *(const f32x4*)(b1 + c);
    f32x4 mv = *(const f32x4*)(m1 + c);
    f32x4 vv = *(const f32x4*)(v1 + c);
    u16x4 ho;
#pragma unroll
    for (int j = 0; j < 4; ++j) {
        float xn = (xv[j] - mv[j]) * rsqrtf(vv[j] + EPS) * gv[j] + bv[j];
        ho[j] = f2bf(silu_d(xn));
    }
    *(u16x4*)(h1 + n * 64 + c) = ho;
}

// ================= conv1: rolled 27-tap dbuf pipeline =================
// h2in = bf16(silu(bn2(sparseconv(h1,W1) + temb[bidx])))
__global__ __launch_bounds__(256) void k_conv1(
        const unsigned short* __restrict__ h1, const int* __restrict__ nbr,
        const unsigned char* __restrict__ mask, const unsigned short* __restrict__ W1s,
        const float* __restrict__ temb, const int* __restrict__ bidx,
        const float* __restrict__ bn2sc, const float* __restrict__ bn2sh,
        unsigned short* __restrict__ h2in, int NV) {
    __shared__ unsigned short lds0[8192];
    __shared__ unsigned short lds1[8192];
    const int lane = threadIdx.x & 63;
    const int wave = threadIdx.x >> 6;
    const int g = lane >> 4, col = lane & 15;
    const int v = blockIdx.x * 64 + wave * 16 + col;
    const bool vok = v < NV;
    const int msh = mask_shift(mask, NV);

    f32x4 acc[8];
    const f32x4 z4 = {0.f, 0.f, 0.f, 0.f};
#pragma unroll
    for (int m = 0; m < 8; ++m) acc[m] = z4;
    const s16x8 zz = {0, 0, 0, 0, 0, 0, 0, 0};

    // row loader: -1 if masked off
    auto loadr = [&](int t) -> int {
        if (!vok) return -1;
        int off = t * NV + v;
        int nv = nbr[off];
        bool mm = mask[(size_t)off << msh] != 0;
        return mm ? nv : -1;
    };

    // prologue: stage tap0 -> buf0; rows tap0/tap1; B(tap0)
    {
        const char* src = (const char*)W1s + (size_t)threadIdx.x * 16;
        char* dst = (char*)lds0 + (size_t)threadIdx.x * 16;
#pragma unroll
        for (int i = 0; i < 4; ++i)
            gload_lds16(src + i * 4096, dst + i * 4096);
    }
    int rA = loadr(0);
    int rN = loadr(1);
    int r0 = rA < 0 ? 0 : rA;
    s16x8 p0 = *(const s16x8*)(h1 + r0 * 64 + 0 * 32 + g * 8);
    s16x8 p1 = *(const s16x8*)(h1 + r0 * 64 + 1 * 32 + g * 8);
    __syncthreads();

    unsigned short* bufc = lds0;
    unsigned short* bufn = lds1;

    for (int t = 0; t < 27; ++t) {
        s16x8 q0, q1;
        int rN2 = -1;
        if (t < 26) {
            // stage tap t+1 into idle buffer
            const char* src = (const char*)W1s + (size_t)(t + 1) * 16384 + (size_t)threadIdx.x * 16;
            char* dst = (char*)bufn + (size_t)threadIdx.x * 16;
#pragma unroll
            for (int i = 0; i < 4; ++i)
                gload_lds16(src + i * 4096, dst + i * 4096);
            // prefetch B for tap t+1
            int rn = rN < 0 ? 0 : rN;
            q0 = *(const s16x8*)(h1 + rn * 64 + 0 * 32 + g * 8);
            q1 = *(const s16x8*)(h1 + rn * 64 + 1 * 32 + g * 8);
        }
        if (t < 25) rN2 = loadr(t + 2);
        // compute tap t
        const bool m = rA >= 0;
        s16x8 b0 = m ? p0 : zz;
        s16x8 b1 = m ? p1 : zz;
        const unsigned short* wp = bufc + lane * 8;
#pragma unroll
        for (int mt = 0; mt < 8; ++mt) {
            s16x8 a = *(const s16x8*)(wp + (0 * 8 + mt) * 512);
            acc[mt] = __builtin_amdgcn_mfma_f32_16x16x32_bf16(a, b0, acc[mt], 0, 0, 0);
        }
#pragma unroll
        for (int mt = 0; mt < 8; ++mt) {
            s16x8 a = *(const s16x8*)(wp + (1 * 8 + mt) * 512);
            acc[mt] = __builtin_amdgcn_mfma_f32_16x16x32_bf16(a, b1, acc[mt], 0, 0, 0);
        }
        if (t < 26) {
            __syncthreads();     // stage(t+1)+prefetch complete; reads(t) done
            p0 = q0; p1 = q1;
            rA = rN; rN = rN2;
            unsigned short* tmp = bufc; bufc = bufn; bufn = tmp;
        }
    }

    if (vok) {
        int b = bidx[v];
        const float* te = temb + b * 128;
#pragma unroll
        for (int mt = 0; mt < 8; ++mt) {
            int c = mt * 16 + g * 4;
            f32x4 val = acc[mt];
            f32x4 tv = *(const f32x4*)(te + c);
            f32x4 sc = *(const f32x4*)(bn2sc + c);
            f32x4 sh = *(const f32x4*)(bn2sh + c);
            u16x4 o;
#pragma unroll
            for (int j = 0; j < 4; ++j) {
                float zv = (val[j] + tv[j]) * sc[j] + sh[j];
                o[j] = f2bf(silu_d(zv));
            }
            *(u16x4*)(h2in + v * 128 + c) = o;
        }
    }
}

// ================= conv2: rolled 27-tap x 2-period pipeline + residual =================
// out = sparseconv(h2in,W2) + bf16(x)@res_W + res_b
// buffers fixed per half: buf0 = (t,h0), buf1 = (t,h1). Stage p+1 during p.
// B for tap t gathered during tap t-1 (depth ~2 periods).
__global__ __launch_bounds__(256) void k_conv2(
        const unsigned short* __restrict__ h2in, const int* __restrict__ nbr,
        const unsigned char* __restrict__ mask, const unsigned short* __restrict__ W2s,
        const float* __restrict__ x, const unsigned short* __restrict__ rWs,
        const float* __restrict__ resb, float* __restrict__ out, int NV) {
    __shared__ unsigned short lds0[8192];   // (t, h0) chunks
    __shared__ unsigned short lds1[8192];   // (t, h1) chunks
    const int lane = threadIdx.x & 63;
    const int wave = threadIdx.x >> 6;
    const int g = lane >> 4, col = lane & 15;
    const int v = blockIdx.x * 64 + wave * 16 + col;
    const bool vok = v < NV;
    const int msh = mask_shift(mask, NV);

    f32x4 acc[8];
    const f32x4 z4 = {0.f, 0.f, 0.f, 0.f};
#pragma unroll
    for (int m = 0; m < 8; ++m) acc[m] = z4;
    const s16x8 zz = {0, 0, 0, 0, 0, 0, 0, 0};

    auto loadr = [&](int t) -> int {
        if (!vok) return -1;
        int off = t * NV + v;
        int nv = nbr[off];
        bool mm = mask[(size_t)off << msh] != 0;
        return mm ? nv : -1;
    };

    // prologue: stage (0,h0)->buf0; rows; B(tap0) both halves; residual GEMM
    {
        const char* src = (const char*)W2s + (size_t)threadIdx.x * 16;
        char* dst = (char*)lds0 + (size_t)threadIdx.x * 16;
#pragma unroll
        for (int i = 0; i < 4; ++i)
            gload_lds16(src + i * 4096, dst + i * 4096);
    }
    int rA = loadr(0);
    int rN = loadr(1);
    int r0 = rA < 0 ? 0 : rA;
    s16x8 pA0 = *(const s16x8*)(h2in + r0 * 128 + 0 * 32 + g * 8);
    s16x8 pA1 = *(const s16x8*)(h2in + r0 * 128 + 1 * 32 + g * 8);
    s16x8 pB0 = *(const s16x8*)(h2in + r0 * 128 + 2 * 32 + g * 8);
    s16x8 pB1 = *(const s16x8*)(h2in + r0 * 128 + 3 * 32 + g * 8);

    // residual GEMM while (0,h0) stages
    {
        int rv = vok ? v : 0;
#pragma unroll
        for (int ks = 0; ks < 2; ++ks) {
            f32x4 xa = *(const f32x4*)(x + rv * 64 + ks * 32 + g * 8);
            f32x4 xb = *(const f32x4*)(x + rv * 64 + ks * 32 + g * 8 + 4);
            s16x8 b;
#pragma unroll
            for (int j = 0; j < 4; ++j) {
                b[j]     = (short)f2bf(xa[j]);
                b[j + 4] = (short)f2bf(xb[j]);
            }
            const unsigned short* wp = rWs + ks * 4096 + lane * 8;
#pragma unroll
            for (int mt = 0; mt < 8; ++mt) {
                s16x8 a = *(const s16x8*)(wp + mt * 512);
                acc[mt] = __builtin_amdgcn_mfma_f32_16x16x32_bf16(a, b, acc[mt], 0, 0, 0);
            }
        }
    }
    __syncthreads();   // (0,h0) staged; prologue gathers complete

    for (int t = 0; t < 27; ++t) {
        const bool m = rA >= 0;
        const int rn = rN < 0 ? 0 : rN;
        s16x8 qA0, qA1, qB0, qB1;
        int rN2 = -1;

        // ---- period A: read buf0 = (t,h0) ----
        {
            // stage (t,h1) -> buf1
            const char* src = (const char*)W2s + ((size_t)t * 2 + 1) * 16384 + (size_t)threadIdx.x * 16;
            char* dst = (char*)lds1 + (size_t)threadIdx.x * 16;
#pragma unroll
            for (int i = 0; i < 4; ++i)
                gload_lds16(src + i * 4096, dst + i * 4096);
            if (t < 26) {
                qA0 = *(const s16x8*)(h2in + rn * 128 + 0 * 32 + g * 8);
                qA1 = *(const s16x8*)(h2in + rn * 128 + 1 * 32 + g * 8);
            }
            if (t < 25) rN2 = loadr(t + 2);
            s16x8 b0 = m ? pA0 : zz;
            s16x8 b1 = m ? pA1 : zz;
            const unsigned short* wp = lds0 + lane * 8;
#pragma unroll
            for (int mt = 0; mt < 8; ++mt) {
                s16x8 a = *(const s16x8*)(wp + (0 * 8 + mt) * 512);
                acc[mt] = __builtin_amdgcn_mfma_f32_16x16x32_bf16(a, b0, acc[mt], 0, 0, 0);
            }
#pragma unroll
            for (int mt = 0; mt < 8; ++mt) {
                s16x8 a = *(const s16x8*)(wp + (1 * 8 + mt) * 512);
                acc[mt] = __builtin_amdgcn_mfma_f32_16x16x32_bf16(a, b1, acc[mt], 0, 0, 0);
            }
            __syncthreads();   // (t,h1) staged; A-phase prefetches done
        }

        // ---- period B: read buf1 = (t,h1) ----
        {
            if (t < 26) {
                // stage (t+1,h0) -> buf0
                const char* src = (const char*)W2s + ((size_t)(t + 1) * 2 + 0) * 16384 + (size_t)threadIdx.x * 16;
                char* dst = (char*)lds0 + (size_t)threadIdx.x * 16;
#pragma unroll
                for (int i = 0; i < 4; ++i)
                    gload_lds16(src + i * 4096, dst + i * 4096);
                qB0 = *(const s16x8*)(h2in + rn * 128 + 2 * 32 + g * 8);
                qB1 = *(const s16x8*)(h2in + rn * 128 + 3 * 32 + g * 8);
            }
            s16x8 b0 = m ? pB0 : zz;
            s16x8 b1 = m ? pB1 : zz;
            const unsigned short* wp = lds1 + lane * 8;
#pragma unroll
            for (int mt = 0; mt < 8; ++mt) {
                s16x8 a = *(const s16x8*)(wp + (0 * 8 + mt) * 512);
                acc[mt] = __builtin_amdgcn_mfma_f32_16x16x32_bf16(a, b0, acc[mt], 0, 0, 0);
            }
#pragma unroll
            for (int mt = 0; mt < 8; ++mt) {
                s16x8 a = *(const s16x8*)(wp + (1 * 8 + mt) * 512);
                acc[mt] = __builtin_amdgcn_mfma_f32_16x16x32_bf16(a, b1, acc[mt], 0, 0, 0);
            }
            __syncthreads();   // (t+1,h0) staged; B-phase prefetches done
        }

        pA0 = qA0; pA1 = qA1; pB0 = qB0; pB1 = qB1;
        rA = rN; rN = rN2;
    }

    if (vok) {
#pragma unroll
        for (int mt = 0; mt < 8; ++mt) {
            int c = mt * 16 + g * 4;
            f32x4 rr = acc[mt] + *(const f32x4*)(resb + c);
            *(f32x4*)(out + v * 128 + c) = rr;
        }
    }
}

extern "C" void kernel_launch(void* const* d_in, const int* in_sizes, int n_in,
                              void* d_out, int out_size, void* d_ws, size_t ws_size,
                              hipStream_t stream) {
    const float* x          = (const float*)d_in[0];
    const int* bidx         = (const int*)d_in[1];
    const float* t          = (const float*)d_in[2];
    const int* nbr1         = (const int*)d_in[3];
    const unsigned char* mask1 = (const unsigned char*)d_in[4];
    const int* nbr2         = (const int*)d_in[5];
    const unsigned char* mask2 = (const unsigned char*)d_in[6];
    const float* bn1g       = (const float*)d_in[7];
    const float* bn1b       = (const float*)d_in[8];
    const float* bn1m       = (const float*)d_in[9];
    const float* bn1v       = (const float*)d_in[10];
    const float* W1         = (const float*)d_in[11];
    const float* tW         = (const float*)d_in[12];
    const float* tb         = (const float*)d_in[13];
    const float* bn2g       = (const float*)d_in[14];
    const float* bn2b       = (const float*)d_in[15];
    const float* bn2m       = (const float*)d_in[16];
    const float* bn2v       = (const float*)d_in[17];
    const float* W2         = (const float*)d_in[18];
    const float* rW         = (const float*)d_in[19];
    const float* resb       = (const float*)d_in[20];

    const int NV = in_sizes[0] / 64;
    const int B  = in_sizes[2] / 256;
    float* out = (float*)d_out;

    // workspace layout: small buffers first, total ~20.5 MB
    char* ws = (char*)d_ws;
    size_t o_W1s = 0;
    size_t o_W2s = o_W1s + (size_t)432 * 1024;
    size_t o_rWs = o_W2s + (size_t)864 * 1024;
    size_t o_te  = o_rWs + (size_t)16 * 1024;
    size_t o_sc  = o_te  + (size_t)B * 128 * 4;
    size_t o_sh  = o_sc  + 512;
    size_t o_h1  = o_sh  + 512;
    size_t o_h2  = o_h1  + (size_t)NV * 64 * 2;

    unsigned short* W1s  = (unsigned short*)(ws + o_W1s);
    unsigned short* W2s  = (unsigned short*)(ws + o_W2s);
    unsigned short* rWs  = (unsigned short*)(ws + o_rWs);
    float* temb  = (float*)(ws + o_te);
    float* bn2sc = (float*)(ws + o_sc);
    float* bn2sh = (float*)(ws + o_sh);
    unsigned short* h1   = (unsigned short*)(ws + o_h1);
    unsigned short* h2in = (unsigned short*)(ws + o_h2);

    k_prep_small<<<1, 512, 0, stream>>>(t, tW, tb, bn2g, bn2b, bn2m, bn2v,
                                        temb, bn2sc, bn2sh, B);
    {
        int total = (432 + 864 + 16) * 512;
        int grid = (total + 255) / 256;
        k_shuffle<<<grid, 256, 0, stream>>>(W1, W2, rW, W1s, W2s, rWs);
    }
    {
        int total = NV * 16;
        int grid = (total + 255) / 256;
        k_elem<<<grid, 256, 0, stream>>>(x, bn1g, bn1b, bn1m, bn1v, h1, NV);
    }
    {
        int grid = (NV + 63) / 64;
        k_conv1<<<grid, 256, 0, stream>>>(h1, nbr1, mask1, W1s, temb, bidx,
                                          bn2sc, bn2sh, h2in, NV);
        k_conv2<<<grid, 256, 0, stream>>>(h2in, nbr2, mask2, W2s, x, rWs,
                                          resb, out, NV);
    }
}

// Round 19
// 143.158 us; speedup vs baseline: 1.4197x; 1.1546x over previous
//
#include <hip/hip_runtime.h>

// SparseResidualBlock: bn1->silu->sparseconv1(+t_emb)->bn2->silu->sparseconv2 + (x@res_W+res_b)
// N=50000, FIN=64, FOUT=128, K=27, B=4, TEMB=256. Output f32 [N,128].
//
// R19 = R18 rolled pipeline with 8-WAVE (512-thread) blocks: 128 vox/block,
// grid 391, 2-4 blocks/CU co-resident (16-32 waves/CU vs 7). Same total wave
// count; barrier groups 2x wider; per-CU latency overlap 2-4x. Occupancy was
// the last unexplained counter (22% vs 4-5 block capacity). Everything else
// (16x16x32, 2x16KB dbuf, 1 __syncthreads/period, depth-2 B-prefetch,
// rolled loops) identical to R18 (165us champion).

#define EPS 1e-5f

typedef __attribute__((ext_vector_type(8))) short s16x8;
typedef __attribute__((ext_vector_type(4))) float f32x4;
typedef __attribute__((ext_vector_type(4))) unsigned short u16x4;

static __device__ __forceinline__ unsigned short f2bf(float f) {
    union { float f; unsigned u; } v; v.f = f;
    unsigned r = v.u + 0x7fffu + ((v.u >> 16) & 1u);   // RTNE
    return (unsigned short)(r >> 16);
}
static __device__ __forceinline__ float silu_d(float x) {
    return x / (1.f + __expf(-x));
}
static __device__ __forceinline__ void gload_lds16(const void* gsrc, void* ldst) {
    __builtin_amdgcn_global_load_lds(
        (const __attribute__((address_space(1))) unsigned int*)gsrc,
        (__attribute__((address_space(3))) unsigned int*)ldst, 16, 0, 0);
}
// mask stored as 1-byte bool (shift 0) or int32 (shift 2)? Probe a byte at a
// non-multiple-of-4 index inside the all-true center row (k=13).
static __device__ __forceinline__ int mask_shift(const unsigned char* mask, int NV) {
    size_t base = (size_t)13 * (size_t)NV;
    int v = ((base & 3) == 3) ? 2 : 1;
    return (mask[base + v] == 1) ? 0 : 2;
}

// ---------------- prep: t_emb + bn2 scale/shift ----------------
__global__ void k_prep_small(const float* __restrict__ t, const float* __restrict__ tW,
                             const float* __restrict__ tb,
                             const float* __restrict__ g2, const float* __restrict__ b2,
                             const float* __restrict__ m2, const float* __restrict__ v2,
                             float* __restrict__ temb, float* __restrict__ sc,
                             float* __restrict__ sh, int B) {
    int tid = threadIdx.x;
    if (tid < B * 128) {
        int b = tid >> 7, o = tid & 127;
        float s = 0.f;
        for (int e = 0; e < 256; ++e) {
            float tv = t[b * 256 + e];
            s += silu_d(tv) * tW[e * 128 + o];
        }
        temb[tid] = s + tb[o];
    }
    if (tid < 128) {
        float rstd = rsqrtf(v2[tid] + EPS);
        float s1 = g2[tid] * rstd;
        sc[tid] = s1;
        sh[tid] = b2[tid] - m2[tid] * s1;
    }
}

// ---------------- prep: shuffle weights to fragment-linear bf16 (16x16x32) ----------------
// frag elem[lane*8+j] = W[ko][fin=ks*32+(lane>>4)*8+j][fout=mt*16+(lane&15)]
__global__ __launch_bounds__(256) void k_shuffle(
        const float* __restrict__ W1, const float* __restrict__ W2,
        const float* __restrict__ rW,
        unsigned short* __restrict__ W1s, unsigned short* __restrict__ W2s,
        unsigned short* __restrict__ rWs) {
    int tid = blockIdx.x * 256 + threadIdx.x;
    const int n1 = 432 * 512, n2 = 864 * 512, n3 = 16 * 512;
    if (tid < n1) {
        int f = tid >> 9, r = tid & 511, lane = r >> 3, j = r & 7;
        int mt = f & 7, fk = f >> 3, ks = fk & 1, ko = fk >> 1;
        int fin = ks * 32 + (lane >> 4) * 8 + j;
        int fout = mt * 16 + (lane & 15);
        W1s[tid] = f2bf(W1[(ko * 64 + fin) * 128 + fout]);
    } else if (tid < n1 + n2) {
        int e = tid - n1;
        int f = e >> 9, r = e & 511, lane = r >> 3, j = r & 7;
        int mt = f & 7, fk = f >> 3, ks = fk & 3, ko = fk >> 2;
        int fin = ks * 32 + (lane >> 4) * 8 + j;
        int fout = mt * 16 + (lane & 15);
        W2s[e] = f2bf(W2[(ko * 128 + fin) * 128 + fout]);
    } else if (tid < n1 + n2 + n3) {
        int e = tid - n1 - n2;
        int f = e >> 9, r = e & 511, lane = r >> 3, j = r & 7;
        int mt = f & 7, ks = f >> 3;
        int fin = ks * 32 + (lane >> 4) * 8 + j;
        int fout = mt * 16 + (lane & 15);
        rWs[e] = f2bf(rW[fin * 128 + fout]);
    }
}

// ---------------- elementwise: h1 = bf16(silu(bn1(x))) ----------------
__global__ __launch_bounds__(256) void k_elem(
        const float* __restrict__ x,
        const float* __restrict__ g1, const float* __restrict__ b1,
        const float* __restrict__ m1, const float* __restrict__ v1,
        unsigned short* __restrict__ h1, int NV) {
    int tid = blockIdx.x * 256 + threadIdx.x;
    if (tid >= NV * 16) return;
    int n = tid >> 4, c = (tid & 15) << 2;
    f32x4 xv = *(const f32x4*)(x + n * 64 + c);
    f32x4 gv = *(const f32x4*)(g1 + c);
    f32x4 bv = *(const f32x4*)(b1 + c);
    f32x4 mv = *(const f32x4*)(m1 + c);
    f32x4 vv = *(const f32x4*)(v1 + c);
    u16x4 ho;
#pragma unroll
    for (int j = 0; j < 4; ++j) {
        float xn = (xv[j] - mv[j]) * rsqrtf(vv[j] + EPS) * gv[j] + bv[j];
        ho[j] = f2bf(silu_d(xn));
    }
    *(u16x4*)(h1 + n * 64 + c) = ho;
}

// ================= conv1: 8-wave rolled 27-tap dbuf pipeline =================
// h2in = bf16(silu(bn2(sparseconv(h1,W1) + temb[bidx])))
__global__ __launch_bounds__(512) void k_conv1(
        const unsigned short* __restrict__ h1, const int* __restrict__ nbr,
        const unsigned char* __restrict__ mask, const unsigned short* __restrict__ W1s,
        const float* __restrict__ temb, const int* __restrict__ bidx,
        const float* __restrict__ bn2sc, const float* __restrict__ bn2sh,
        unsigned short* __restrict__ h2in, int NV) {
    __shared__ unsigned short lds0[8192];
    __shared__ unsigned short lds1[8192];
    const int lane = threadIdx.x & 63;
    const int wave = threadIdx.x >> 6;          // 0..7
    const int g = lane >> 4, col = lane & 15;
    const int v = blockIdx.x * 128 + wave * 16 + col;
    const bool vok = v < NV;
    const int msh = mask_shift(mask, NV);

    f32x4 acc[8];
    const f32x4 z4 = {0.f, 0.f, 0.f, 0.f};
#pragma unroll
    for (int m = 0; m < 8; ++m) acc[m] = z4;
    const s16x8 zz = {0, 0, 0, 0, 0, 0, 0, 0};

    auto loadr = [&](int t) -> int {
        if (!vok) return -1;
        int off = t * NV + v;
        int nv = nbr[off];
        bool mm = mask[(size_t)off << msh] != 0;
        return mm ? nv : -1;
    };

    // prologue: stage tap0 -> buf0 (512 thr x 2 x 16B = 16KB); rows; B(tap0)
    {
        const char* src = (const char*)W1s + (size_t)threadIdx.x * 16;
        char* dst = (char*)lds0 + (size_t)threadIdx.x * 16;
#pragma unroll
        for (int i = 0; i < 2; ++i)
            gload_lds16(src + i * 8192, dst + i * 8192);
    }
    int rA = loadr(0);
    int rN = loadr(1);
    int r0 = rA < 0 ? 0 : rA;
    s16x8 p0 = *(const s16x8*)(h1 + r0 * 64 + 0 * 32 + g * 8);
    s16x8 p1 = *(const s16x8*)(h1 + r0 * 64 + 1 * 32 + g * 8);
    __syncthreads();

    unsigned short* bufc = lds0;
    unsigned short* bufn = lds1;

    for (int t = 0; t < 27; ++t) {
        s16x8 q0, q1;
        int rN2 = -1;
        if (t < 26) {
            const char* src = (const char*)W1s + (size_t)(t + 1) * 16384 + (size_t)threadIdx.x * 16;
            char* dst = (char*)bufn + (size_t)threadIdx.x * 16;
#pragma unroll
            for (int i = 0; i < 2; ++i)
                gload_lds16(src + i * 8192, dst + i * 8192);
            int rn = rN < 0 ? 0 : rN;
            q0 = *(const s16x8*)(h1 + rn * 64 + 0 * 32 + g * 8);
            q1 = *(const s16x8*)(h1 + rn * 64 + 1 * 32 + g * 8);
        }
        if (t < 25) rN2 = loadr(t + 2);
        const bool m = rA >= 0;
        s16x8 b0 = m ? p0 : zz;
        s16x8 b1 = m ? p1 : zz;
        const unsigned short* wp = bufc + lane * 8;
#pragma unroll
        for (int mt = 0; mt < 8; ++mt) {
            s16x8 a = *(const s16x8*)(wp + (0 * 8 + mt) * 512);
            acc[mt] = __builtin_amdgcn_mfma_f32_16x16x32_bf16(a, b0, acc[mt], 0, 0, 0);
        }
#pragma unroll
        for (int mt = 0; mt < 8; ++mt) {
            s16x8 a = *(const s16x8*)(wp + (1 * 8 + mt) * 512);
            acc[mt] = __builtin_amdgcn_mfma_f32_16x16x32_bf16(a, b1, acc[mt], 0, 0, 0);
        }
        if (t < 26) {
            __syncthreads();
            p0 = q0; p1 = q1;
            rA = rN; rN = rN2;
            unsigned short* tmp = bufc; bufc = bufn; bufn = tmp;
        }
    }

    if (vok) {
        int b = bidx[v];
        const float* te = temb + b * 128;
#pragma unroll
        for (int mt = 0; mt < 8; ++mt) {
            int c = mt * 16 + g * 4;
            f32x4 val = acc[mt];
            f32x4 tv = *(const f32x4*)(te + c);
            f32x4 sc = *(const f32x4*)(bn2sc + c);
            f32x4 sh = *(const f32x4*)(bn2sh + c);
            u16x4 o;
#pragma unroll
            for (int j = 0; j < 4; ++j) {
                float zv = (val[j] + tv[j]) * sc[j] + sh[j];
                o[j] = f2bf(silu_d(zv));
            }
            *(u16x4*)(h2in + v * 128 + c) = o;
        }
    }
}

// ================= conv2: 8-wave rolled 27-tap x 2-period pipeline + residual =================
__global__ __launch_bounds__(512) void k_conv2(
        const unsigned short* __restrict__ h2in, const int* __restrict__ nbr,
        const unsigned char* __restrict__ mask, const unsigned short* __restrict__ W2s,
        const float* __restrict__ x, const unsigned short* __restrict__ rWs,
        const float* __restrict__ resb, float* __restrict__ out, int NV) {
    __shared__ unsigned short lds0[8192];   // (t, h0) chunks
    __shared__ unsigned short lds1[8192];   // (t, h1) chunks
    const int lane = threadIdx.x & 63;
    const int wave = threadIdx.x >> 6;      // 0..7
    const int g = lane >> 4, col = lane & 15;
    const int v = blockIdx.x * 128 + wave * 16 + col;
    const bool vok = v < NV;
    const int msh = mask_shift(mask, NV);

    f32x4 acc[8];
    const f32x4 z4 = {0.f, 0.f, 0.f, 0.f};
#pragma unroll
    for (int m = 0; m < 8; ++m) acc[m] = z4;
    const s16x8 zz = {0, 0, 0, 0, 0, 0, 0, 0};

    auto loadr = [&](int t) -> int {
        if (!vok) return -1;
        int off = t * NV + v;
        int nv = nbr[off];
        bool mm = mask[(size_t)off << msh] != 0;
        return mm ? nv : -1;
    };

    // prologue: stage (0,h0)->buf0; rows; B(tap0); residual GEMM
    {
        const char* src = (const char*)W2s + (size_t)threadIdx.x * 16;
        char* dst = (char*)lds0 + (size_t)threadIdx.x * 16;
#pragma unroll
        for (int i = 0; i < 2; ++i)
            gload_lds16(src + i * 8192, dst + i * 8192);
    }
    int rA = loadr(0);
    int rN = loadr(1);
    int r0 = rA < 0 ? 0 : rA;
    s16x8 pA0 = *(const s16x8*)(h2in + r0 * 128 + 0 * 32 + g * 8);
    s16x8 pA1 = *(const s16x8*)(h2in + r0 * 128 + 1 * 32 + g * 8);
    s16x8 pB0 = *(const s16x8*)(h2in + r0 * 128 + 2 * 32 + g * 8);
    s16x8 pB1 = *(const s16x8*)(h2in + r0 * 128 + 3 * 32 + g * 8);

    // residual GEMM while (0,h0) stages
    {
        int rv = vok ? v : 0;
#pragma unroll
        for (int ks = 0; ks < 2; ++ks) {
            f32x4 xa = *(const f32x4*)(x + rv * 64 + ks * 32 + g * 8);
            f32x4 xb = *(const f32x4*)(x + rv * 64 + ks * 32 + g * 8 + 4);
            s16x8 b;
#pragma unroll
            for (int j = 0; j < 4; ++j) {
                b[j]     = (short)f2bf(xa[j]);
                b[j + 4] = (short)f2bf(xb[j]);
            }
            const unsigned short* wp = rWs + ks * 4096 + lane * 8;
#pragma unroll
            for (int mt = 0; mt < 8; ++mt) {
                s16x8 a = *(const s16x8*)(wp + mt * 512);
                acc[mt] = __builtin_amdgcn_mfma_f32_16x16x32_bf16(a, b, acc[mt], 0, 0, 0);
            }
        }
    }
    __syncthreads();   // (0,h0) staged; prologue gathers complete

    for (int t = 0; t < 27; ++t) {
        const bool m = rA >= 0;
        const int rn = rN < 0 ? 0 : rN;
        s16x8 qA0, qA1, qB0, qB1;
        int rN2 = -1;

        // ---- period A: read buf0 = (t,h0) ----
        {
            const char* src = (const char*)W2s + ((size_t)t * 2 + 1) * 16384 + (size_t)threadIdx.x * 16;
            char* dst = (char*)lds1 + (size_t)threadIdx.x * 16;
#pragma unroll
            for (int i = 0; i < 2; ++i)
                gload_lds16(src + i * 8192, dst + i * 8192);
            if (t < 26) {
                qA0 = *(const s16x8*)(h2in + rn * 128 + 0 * 32 + g * 8);
                qA1 = *(const s16x8*)(h2in + rn * 128 + 1 * 32 + g * 8);
            }
            if (t < 25) rN2 = loadr(t + 2);
            s16x8 b0 = m ? pA0 : zz;
            s16x8 b1 = m ? pA1 : zz;
            const unsigned short* wp = lds0 + lane * 8;
#pragma unroll
            for (int mt = 0; mt < 8; ++mt) {
                s16x8 a = *(const s16x8*)(wp + (0 * 8 + mt) * 512);
                acc[mt] = __builtin_amdgcn_mfma_f32_16x16x32_bf16(a, b0, acc[mt], 0, 0, 0);
            }
#pragma unroll
            for (int mt = 0; mt < 8; ++mt) {
                s16x8 a = *(const s16x8*)(wp + (1 * 8 + mt) * 512);
                acc[mt] = __builtin_amdgcn_mfma_f32_16x16x32_bf16(a, b1, acc[mt], 0, 0, 0);
            }
            __syncthreads();   // (t,h1) staged; A-phase prefetches done
        }

        // ---- period B: read buf1 = (t,h1) ----
        {
            if (t < 26) {
                const char* src = (const char*)W2s + ((size_t)(t + 1) * 2 + 0) * 16384 + (size_t)threadIdx.x * 16;
                char* dst = (char*)lds0 + (size_t)threadIdx.x * 16;
#pragma unroll
                for (int i = 0; i < 2; ++i)
                    gload_lds16(src + i * 8192, dst + i * 8192);
                qB0 = *(const s16x8*)(h2in + rn * 128 + 2 * 32 + g * 8);
                qB1 = *(const s16x8*)(h2in + rn * 128 + 3 * 32 + g * 8);
            }
            s16x8 b0 = m ? pB0 : zz;
            s16x8 b1 = m ? pB1 : zz;
            const unsigned short* wp = lds1 + lane * 8;
#pragma unroll
            for (int mt = 0; mt < 8; ++mt) {
                s16x8 a = *(const s16x8*)(wp + (0 * 8 + mt) * 512);
                acc[mt] = __builtin_amdgcn_mfma_f32_16x16x32_bf16(a, b0, acc[mt], 0, 0, 0);
            }
#pragma unroll
            for (int mt = 0; mt < 8; ++mt) {
                s16x8 a = *(const s16x8*)(wp + (1 * 8 + mt) * 512);
                acc[mt] = __builtin_amdgcn_mfma_f32_16x16x32_bf16(a, b1, acc[mt], 0, 0, 0);
            }
            __syncthreads();   // (t+1,h0) staged; B-phase prefetches done
        }

        pA0 = qA0; pA1 = qA1; pB0 = qB0; pB1 = qB1;
        rA = rN; rN = rN2;
    }

    if (vok) {
#pragma unroll
        for (int mt = 0; mt < 8; ++mt) {
            int c = mt * 16 + g * 4;
            f32x4 rr = acc[mt] + *(const f32x4*)(resb + c);
            *(f32x4*)(out + v * 128 + c) = rr;
        }
    }
}

extern "C" void kernel_launch(void* const* d_in, const int* in_sizes, int n_in,
                              void* d_out, int out_size, void* d_ws, size_t ws_size,
                              hipStream_t stream) {
    const float* x          = (const float*)d_in[0];
    const int* bidx         = (const int*)d_in[1];
    const float* t          = (const float*)d_in[2];
    const int* nbr1         = (const int*)d_in[3];
    const unsigned char* mask1 = (const unsigned char*)d_in[4];
    const int* nbr2         = (const int*)d_in[5];
    const unsigned char* mask2 = (const unsigned char*)d_in[6];
    const float* bn1g       = (const float*)d_in[7];
    const float* bn1b       = (const float*)d_in[8];
    const float* bn1m       = (const float*)d_in[9];
    const float* bn1v       = (const float*)d_in[10];
    const float* W1         = (const float*)d_in[11];
    const float* tW         = (const float*)d_in[12];
    const float* tb         = (const float*)d_in[13];
    const float* bn2g       = (const float*)d_in[14];
    const float* bn2b       = (const float*)d_in[15];
    const float* bn2m       = (const float*)d_in[16];
    const float* bn2v       = (const float*)d_in[17];
    const float* W2         = (const float*)d_in[18];
    const float* rW         = (const float*)d_in[19];
    const float* resb       = (const float*)d_in[20];

    const int NV = in_sizes[0] / 64;
    const int B  = in_sizes[2] / 256;
    float* out = (float*)d_out;

    // workspace layout: small buffers first, total ~20.5 MB
    char* ws = (char*)d_ws;
    size_t o_W1s = 0;
    size_t o_W2s = o_W1s + (size_t)432 * 1024;
    size_t o_rWs = o_W2s + (size_t)864 * 1024;
    size_t o_te  = o_rWs + (size_t)16 * 1024;
    size_t o_sc  = o_te  + (size_t)B * 128 * 4;
    size_t o_sh  = o_sc  + 512;
    size_t o_h1  = o_sh  + 512;
    size_t o_h2  = o_h1  + (size_t)NV * 64 * 2;

    unsigned short* W1s  = (unsigned short*)(ws + o_W1s);
    unsigned short* W2s  = (unsigned short*)(ws + o_W2s);
    unsigned short* rWs  = (unsigned short*)(ws + o_rWs);
    float* temb  = (float*)(ws + o_te);
    float* bn2sc = (float*)(ws + o_sc);
    float* bn2sh = (float*)(ws + o_sh);
    unsigned short* h1   = (unsigned short*)(ws + o_h1);
    unsigned short* h2in = (unsigned short*)(ws + o_h2);

    k_prep_small<<<1, 512, 0, stream>>>(t, tW, tb, bn2g, bn2b, bn2m, bn2v,
                                        temb, bn2sc, bn2sh, B);
    {
        int total = (432 + 864 + 16) * 512;
        int grid = (total + 255) / 256;
        k_shuffle<<<grid, 256, 0, stream>>>(W1, W2, rW, W1s, W2s, rWs);
    }
    {
        int total = NV * 16;
        int grid = (total + 255) / 256;
        k_elem<<<grid, 256, 0, stream>>>(x, bn1g, bn1b, bn1m, bn1v, h1, NV);
    }
    {
        int grid = (NV + 127) / 128;
        k_conv1<<<grid, 512, 0, stream>>>(h1, nbr1, mask1, W1s, temb, bidx,
                                          bn2sc, bn2sh, h2in, NV);
        k_conv2<<<grid, 512, 0, stream>>>(h2in, nbr2, mask2, W2s, x, rWs,
                                          resb, out, NV);
    }
}